// Round 1
// baseline (404.194 us; speedup 1.0000x reference)
//
#include <hip/hip_runtime.h>

#define NT 256

// ---------------- workspace layout (float offsets) ----------------
#define WS_SPWT    0        // [128][64]  sp_w transposed: spwT[c][h] = sp_w[h][c]
#define WS_SC1     8192     // [128] bn1 scale
#define WS_SH1     8320     // [128] bn1 shift (conv_b folded)
#define WS_SC2     8448     // [128] bn2 scale
#define WS_SH2     8576     // [128] bn2 shift
#define WS_LIWT    8704     // [128][64]  li_wT[j][o] = li_w[o][j]
#define WS_TW1T    16896    // [150][64]  tda_w1T[i][o]
#define WS_TW2T    26496    // [64][32]   tda_w2T[j][o2]
#define WS_CW1T    28544    // [672][128] cls_w1T[j][c]
#define WS_TOTAL   114560

// ---------------- prep: transposes + BN folds ----------------
__global__ void prep_kernel(
    const float* __restrict__ conv_b, const float* __restrict__ bn1_g,
    const float* __restrict__ bn1_b,  const float* __restrict__ bn1_m,
    const float* __restrict__ bn1_v,  const float* __restrict__ sp_w,
    const float* __restrict__ li_w,   const float* __restrict__ tda_w1,
    const float* __restrict__ tda_w2, const float* __restrict__ cls_w1,
    const float* __restrict__ bn2_g,  const float* __restrict__ bn2_b,
    const float* __restrict__ bn2_m,  const float* __restrict__ bn2_v,
    float* __restrict__ ws)
{
    int i = blockIdx.x * NT + threadIdx.x;
    if (i >= WS_TOTAL) return;
    if (i < WS_SC1) {                       // spwT
        int c = i >> 6, h = i & 63;
        ws[i] = sp_w[h*128 + c];
    } else if (i < WS_SH1) {                // bn1 scale
        int c = i - WS_SC1;
        float vv = bn1_v[c] + 1e-5f;
        ws[i] = (float)((double)bn1_g[c] / sqrt((double)vv));
    } else if (i < WS_SC2) {                // bn1 shift
        int c = i - WS_SH1;
        float vv = bn1_v[c] + 1e-5f;
        double s = (double)bn1_g[c] / sqrt((double)vv);
        ws[i] = (float)(((double)conv_b[c] - (double)bn1_m[c])*s + (double)bn1_b[c]);
    } else if (i < WS_SH2) {                // bn2 scale
        int c = i - WS_SC2;
        float vv = bn2_v[c] + 1e-5f;
        ws[i] = (float)((double)bn2_g[c] / sqrt((double)vv));
    } else if (i < WS_LIWT) {               // bn2 shift
        int c = i - WS_SH2;
        float vv = bn2_v[c] + 1e-5f;
        double s = (double)bn2_g[c] / sqrt((double)vv);
        ws[i] = (float)((double)bn2_b[c] - (double)bn2_m[c]*s);
    } else if (i < WS_TW1T) {               // li_wT
        int t = i - WS_LIWT; int j = t >> 6, o = t & 63;
        ws[i] = li_w[o*128 + j];
    } else if (i < WS_TW2T) {               // tda_w1T
        int t = i - WS_TW1T; int r = t >> 6, o = t & 63;
        ws[i] = tda_w1[o*150 + r];
    } else if (i < WS_CW1T) {               // tda_w2T
        int t = i - WS_TW2T; int j = t >> 5, o = t & 31;
        ws[i] = tda_w2[o*64 + j];
    } else {                                // cls_w1T
        int t = i - WS_CW1T; int j = t >> 7, c = t & 127;
        ws[i] = cls_w1[c*672 + j];
    }
}

// ---------------- main fused kernel: one block per batch element ----------------
// LDS map (floats): x[78*64]=4992 | y[128*65]=8320 | cur[64*65]=4160 | W[10*128]=1280 | Wg[10]
__launch_bounds__(NT, 2)
__global__ void snn_kernel(
    const float* __restrict__ x,      const float* __restrict__ tda,
    const float* __restrict__ conv_w, const float* __restrict__ sp_b,
    const float* __restrict__ li_b,
    const float* __restrict__ tda_b1, const float* __restrict__ tda_b2,
    const float* __restrict__ cls_b1, const float* __restrict__ cls_w2,
    const float* __restrict__ cls_b2,
    const float* __restrict__ ws, float* __restrict__ out)
{
    __shared__ float smem[18762];
    float* x_lds   = smem;            // [78][64]   (stride 64)
    float* y_lds   = smem + 4992;     // [128][65]  (stride 65)
    float* cur_lds = smem + 13312;    // [64][65]
    float* W_lds   = smem + 17472;    // [10][128]
    float* Wg_lds  = smem + 18752;    // [10]

    const int tid  = threadIdx.x;
    const int b    = blockIdx.x;
    const int lane = tid & 63;

    // conv persistent per-thread constants (channel cc = tid & 127)
    const int cc   = tid & 127;
    const int half = tid >> 7;        // which 32-t half this thread convolves
    float cwr[15];
    #pragma unroll
    for (int k = 0; k < 15; ++k) cwr[k] = conv_w[cc*15 + k];
    const float sc1 = ws[WS_SC1 + cc];
    const float sh1 = ws[WS_SH1 + cc];

    // matmul: wave-uniform h-tile base
    const int h0 = __builtin_amdgcn_readfirstlane((tid >> 6) << 4);
    const float* __restrict__ spwT = ws;   // [128][64]

    // scan state (used by wave 0; lane = hidden unit h)
    float mf = 0.f, ms = 0.f, rlo = 0.f, rhi = 0.f, g = 0.f;
    const float spb = sp_b[lane];

    const float* xb = x + (size_t)b * (320*64);

    for (int chk = 0; chk < 5; ++chk) {
        const int t0 = chk * 64;
        // ---- stage x chunk (+/-7 halo) into LDS, [trow][ic] ----
        for (int idx = tid; idx < 78*16; idx += NT) {
            int trow = idx >> 4, icq = idx & 15;
            int t = t0 - 7 + trow;
            float4 v = make_float4(0.f, 0.f, 0.f, 0.f);
            if (t >= 0 && t < 320)
                v = *reinterpret_cast<const float4*>(xb + t*64 + icq*4);
            *reinterpret_cast<float4*>(&x_lds[trow*64 + icq*4]) = v;
        }
        __syncthreads();
        // ---- depthwise conv + BN + ReLU -> y_lds[c][tt] ----
        {
            float xr[46];
            #pragma unroll
            for (int r = 0; r < 46; ++r)
                xr[r] = x_lds[(half*32 + r)*64 + (cc >> 1)];
            #pragma unroll
            for (int i = 0; i < 32; ++i) {
                float acc = 0.f;
                #pragma unroll
                for (int k = 0; k < 15; ++k)
                    acc = fmaf(xr[i + k], cwr[k], acc);
                y_lds[cc*65 + half*32 + i] = fmaxf(fmaf(acc, sc1, sh1), 0.f);
            }
        }
        __syncthreads();
        // ---- projection: cur[tt=lane][h0..h0+15] = sum_c y[tt][c]*spwT[c][h] ----
        {
            float acc[16];
            #pragma unroll
            for (int j = 0; j < 16; ++j) acc[j] = 0.f;
            #pragma unroll 4
            for (int c = 0; c < 128; ++c) {
                float yv = y_lds[c*65 + lane];
                const float4* wp = reinterpret_cast<const float4*>(spwT + c*64 + h0);
                float4 w0 = wp[0], w1 = wp[1], w2 = wp[2], w3 = wp[3];
                acc[0]  = fmaf(yv, w0.x, acc[0]);
                acc[1]  = fmaf(yv, w0.y, acc[1]);
                acc[2]  = fmaf(yv, w0.z, acc[2]);
                acc[3]  = fmaf(yv, w0.w, acc[3]);
                acc[4]  = fmaf(yv, w1.x, acc[4]);
                acc[5]  = fmaf(yv, w1.y, acc[5]);
                acc[6]  = fmaf(yv, w1.z, acc[6]);
                acc[7]  = fmaf(yv, w1.w, acc[7]);
                acc[8]  = fmaf(yv, w2.x, acc[8]);
                acc[9]  = fmaf(yv, w2.y, acc[9]);
                acc[10] = fmaf(yv, w2.z, acc[10]);
                acc[11] = fmaf(yv, w2.w, acc[11]);
                acc[12] = fmaf(yv, w3.x, acc[12]);
                acc[13] = fmaf(yv, w3.y, acc[13]);
                acc[14] = fmaf(yv, w3.z, acc[14]);
                acc[15] = fmaf(yv, w3.w, acc[15]);
            }
            #pragma unroll
            for (int j = 0; j < 16; ++j)
                cur_lds[lane*65 + h0 + j] = acc[j];
        }
        __syncthreads();
        // ---- LIF scan, 64 steps, wave 0 only (lane = h, fully lane-local) ----
        if (tid < 64) {
            #pragma unroll
            for (int hb = 0; hb < 2; ++hb) {       // 2 windows per chunk
                float sE_lo=0.f, sE_hi=0.f, sL_lo=0.f, sL_hi=0.f, sE_g=0.f, sL_g=0.f;
                #pragma unroll
                for (int l4 = 0; l4 < 2; ++l4) {   // early half / late half
                    float buf[16];
                    #pragma unroll
                    for (int q = 0; q < 16; ++q)
                        buf[q] = cur_lds[(hb*32 + l4*16 + q)*65 + lane];
                    #pragma unroll
                    for (int q = 0; q < 16; ++q) {
                        float cur = buf[q] + spb;
                        mf = fmaf(0.5f, mf, cur);
                        bool sf = (mf - 0.5f) >= 0.f;
                        ms = fmaf(0.9f, ms, cur);
                        bool ss = (ms - 1.0f) >= 0.f;
                        mf = sf ? 0.f : mf;
                        ms = ss ? 0.f : ms;
                        rlo = fmaf(0.9f, rlo, sf ? 1.f : 0.f);
                        rhi = fmaf(0.9f, rhi, ss ? 1.f : 0.f);
                        g   = fmaf(0.9f, g, 1.f);
                        if (l4 == 0) { sE_lo += rlo; sE_hi += rhi; sE_g += g; }
                        else         { sL_lo += rlo; sL_hi += rhi; sL_g += g; }
                    }
                }
                int w = chk*2 + hb;
                W_lds[w*128 + lane]      = sL_lo - sE_lo;
                W_lds[w*128 + 64 + lane] = sL_hi - sE_hi;
                if (lane == 0) Wg_lds[w] = sL_g - sE_g;
            }
        }
        __syncthreads();
    }

    // ================= fused classifier epilogue =================
    float* t1 = x_lds;        // [64]
    float* tf = x_lds + 64;   // [32]
    float* dp = x_lds + 96;   // [640]
    float* h1 = x_lds + 736;  // [128]

    const float* __restrict__ liwT = ws + WS_LIWT;
    const float* __restrict__ tw1T = ws + WS_TW1T;
    const float* __restrict__ tw2T = ws + WS_TW2T;
    const float* __restrict__ cw1T = ws + WS_CW1T;
    const float* tdab = tda + b*150;

    if (tid < 64) {                     // tda layer 1
        float acc = tda_b1[tid];
        for (int i2 = 0; i2 < 150; ++i2)
            acc = fmaf(tdab[i2], tw1T[i2*64 + tid], acc);
        t1[tid] = fmaxf(acc, 0.f);
    }
    __syncthreads();
    if (tid < 32) {                     // tda layer 2
        float acc = tda_b2[tid];
        #pragma unroll 8
        for (int j = 0; j < 64; ++j)
            acc = fmaf(t1[j], tw2T[j*32 + tid], acc);
        tf[tid] = fmaxf(acc, 0.f);
    }
    // dp_feat = (1/16) * (li_w @ W + li_b * Wg)   (all threads)
    {
        int o = tid & 63;
        for (int w = tid >> 6; w < 10; w += 4) {
            float acc = li_b[o] * Wg_lds[w];
            #pragma unroll 4
            for (int j = 0; j < 128; ++j)
                acc = fmaf(W_lds[w*128 + j], liwT[j*64 + o], acc);
            dp[w*64 + o] = 0.0625f * acc;
        }
    }
    __syncthreads();
    if (tid < 128) {                    // classifier layer 1 + BN2 + ReLU
        float acc = cls_b1[tid];
        for (int j = 0; j < 640; ++j)
            acc = fmaf(dp[j], cw1T[j*128 + tid], acc);
        #pragma unroll 4
        for (int j = 0; j < 32; ++j)
            acc = fmaf(tf[j], cw1T[(640 + j)*128 + tid], acc);
        float s2 = ws[WS_SC2 + tid], sh2 = ws[WS_SH2 + tid];
        h1[tid] = fmaxf(fmaf(acc, s2, sh2), 0.f);
    }
    __syncthreads();
    if (tid < 4) {                      // classifier layer 2
        float acc = cls_b2[tid];
        for (int c = 0; c < 128; ++c)
            acc = fmaf(h1[c], cls_w2[tid*128 + c], acc);
        out[b*4 + tid] = acc;
    }
}

extern "C" void kernel_launch(void* const* d_in, const int* in_sizes, int n_in,
                              void* d_out, int out_size, void* d_ws, size_t ws_size,
                              hipStream_t stream) {
    const float* x      = (const float*)d_in[0];
    const float* tda    = (const float*)d_in[1];
    const float* conv_w = (const float*)d_in[2];
    const float* conv_b = (const float*)d_in[3];
    const float* bn1_g  = (const float*)d_in[4];
    const float* bn1_b  = (const float*)d_in[5];
    const float* bn1_m  = (const float*)d_in[6];
    const float* bn1_v  = (const float*)d_in[7];
    const float* sp_w   = (const float*)d_in[8];
    const float* sp_b   = (const float*)d_in[9];
    const float* li_w   = (const float*)d_in[10];
    const float* li_b   = (const float*)d_in[11];
    const float* tda_w1 = (const float*)d_in[12];
    const float* tda_b1 = (const float*)d_in[13];
    const float* tda_w2 = (const float*)d_in[14];
    const float* tda_b2 = (const float*)d_in[15];
    const float* cls_w1 = (const float*)d_in[16];
    const float* cls_b1 = (const float*)d_in[17];
    const float* bn2_g  = (const float*)d_in[18];
    const float* bn2_b  = (const float*)d_in[19];
    const float* bn2_m  = (const float*)d_in[20];
    const float* bn2_v  = (const float*)d_in[21];
    const float* cls_w2 = (const float*)d_in[22];
    const float* cls_b2 = (const float*)d_in[23];
    float* ws  = (float*)d_ws;
    float* out = (float*)d_out;

    int B = in_sizes[0] / (320 * 64);   // 2048

    prep_kernel<<<(WS_TOTAL + NT - 1)/NT, NT, 0, stream>>>(
        conv_b, bn1_g, bn1_b, bn1_m, bn1_v, sp_w,
        li_w, tda_w1, tda_w2, cls_w1,
        bn2_g, bn2_b, bn2_m, bn2_v, ws);

    snn_kernel<<<B, NT, 0, stream>>>(
        x, tda, conv_w, sp_b, li_b, tda_b1, tda_b2,
        cls_b1, cls_w2, cls_b2, ws, out);
}

// Round 2
// 292.035 us; speedup vs baseline: 1.3841x; 1.3841x over previous
//
#include <hip/hip_runtime.h>

#define NT 256

// ---------------- workspace layout (float offsets) ----------------
#define WS_SPWT    0        // [128][64]  sp_w transposed: spwT[c][h] = sp_w[h][c]
#define WS_SC1     8192     // [128] bn1 scale
#define WS_SH1     8320     // [128] bn1 shift (conv_b folded)
#define WS_SC2     8448     // [128] bn2 scale
#define WS_SH2     8576     // [128] bn2 shift
#define WS_LIWT    8704     // [128][64]  li_wT[j][o] = li_w[o][j]
#define WS_TW1T    16896    // [150][64]  tda_w1T[i][o]
#define WS_TW2T    26496    // [64][32]   tda_w2T[j][o2]
#define WS_CW1T    28544    // [672][128] cls_w1T[j][c]
#define WS_TOTAL   114560   // end of transposed tables
#define WS_WG      114560   // [10] Wg window constants
#define WS_WBASE   114688   // [B][10][128] window features (persistent)
#define WS_CURBASE (114688 + 2048*1280)   // cur region (reused per group)
#define CUR_STRIDE 20480    // 64*320 floats per b

// ---------------- prep: transposes + BN folds + Wg ----------------
__global__ void prep_kernel(
    const float* __restrict__ conv_b, const float* __restrict__ bn1_g,
    const float* __restrict__ bn1_b,  const float* __restrict__ bn1_m,
    const float* __restrict__ bn1_v,  const float* __restrict__ sp_w,
    const float* __restrict__ li_w,   const float* __restrict__ tda_w1,
    const float* __restrict__ tda_w2, const float* __restrict__ cls_w1,
    const float* __restrict__ bn2_g,  const float* __restrict__ bn2_b,
    const float* __restrict__ bn2_m,  const float* __restrict__ bn2_v,
    float* __restrict__ ws)
{
    int i = blockIdx.x * NT + threadIdx.x;
    if (i > WS_TOTAL) return;
    if (i == WS_TOTAL) {                    // Wg[10]: data-independent li-bias windows
        float g = 0.f, sE = 0.f, sL = 0.f; int w = 0;
        for (int t = 0; t < 320; ++t) {
            g = fmaf(0.9f, g, 1.f);
            int pos = t & 31;
            if (pos < 16) sE += g; else sL += g;
            if (pos == 31) { ws[WS_WG + w] = sL - sE; ++w; sE = 0.f; sL = 0.f; }
        }
        return;
    }
    if (i < WS_SC1) {                       // spwT
        int c = i >> 6, h = i & 63;
        ws[i] = sp_w[h*128 + c];
    } else if (i < WS_SH1) {                // bn1 scale
        int c = i - WS_SC1;
        float vv = bn1_v[c] + 1e-5f;
        ws[i] = (float)((double)bn1_g[c] / sqrt((double)vv));
    } else if (i < WS_SC2) {                // bn1 shift
        int c = i - WS_SH1;
        float vv = bn1_v[c] + 1e-5f;
        double s = (double)bn1_g[c] / sqrt((double)vv);
        ws[i] = (float)(((double)conv_b[c] - (double)bn1_m[c])*s + (double)bn1_b[c]);
    } else if (i < WS_SH2) {                // bn2 scale
        int c = i - WS_SC2;
        float vv = bn2_v[c] + 1e-5f;
        ws[i] = (float)((double)bn2_g[c] / sqrt((double)vv));
    } else if (i < WS_LIWT) {               // bn2 shift
        int c = i - WS_SH2;
        float vv = bn2_v[c] + 1e-5f;
        double s = (double)bn2_g[c] / sqrt((double)vv);
        ws[i] = (float)((double)bn2_b[c] - (double)bn2_m[c]*s);
    } else if (i < WS_TW1T) {               // li_wT
        int t = i - WS_LIWT; int j = t >> 6, o = t & 63;
        ws[i] = li_w[o*128 + j];
    } else if (i < WS_TW2T) {               // tda_w1T
        int t = i - WS_TW1T; int r = t >> 6, o = t & 63;
        ws[i] = tda_w1[o*150 + r];
    } else if (i < WS_CW1T) {               // tda_w2T
        int t = i - WS_TW2T; int j = t >> 5, o = t & 31;
        ws[i] = tda_w2[o*64 + j];
    } else {                                // cls_w1T
        int t = i - WS_CW1T; int j = t >> 7, c = t & 127;
        ws[i] = cls_w1[c*672 + j];
    }
}

// ---------------- kernel A: depthwise conv + BN + ReLU + 128->64 projection ----
// one block per (b, 64-t chunk); writes cur[bi][h][t] (group-local bi)
__launch_bounds__(NT, 3)
__global__ void convproj_kernel(
    const float* __restrict__ x, const float* __restrict__ conv_w,
    const float* __restrict__ ws, float* __restrict__ cur, int b0)
{
    __shared__ float smem[13312];
    float* x_lds = smem;          // [78][64]  stride 64
    float* y_lds = smem + 4992;   // [128][65] stride 65

    const int tid  = threadIdx.x;
    const int bi   = blockIdx.x / 5;
    const int chk  = blockIdx.x % 5;
    const int b    = b0 + bi;
    const int lane = tid & 63;
    const int t0   = chk * 64;

    const int cc   = tid & 127;
    const int half = tid >> 7;
    float cwr[15];
    #pragma unroll
    for (int k = 0; k < 15; ++k) cwr[k] = conv_w[cc*15 + k];
    const float sc1 = ws[WS_SC1 + cc];
    const float sh1 = ws[WS_SH1 + cc];

    const int h0 = __builtin_amdgcn_readfirstlane((tid >> 6) << 4);
    const float* __restrict__ spwT = ws;   // [128][64]
    const float* xb = x + (size_t)b * 20480;

    // ---- stage x chunk (+/-7 halo) into LDS ----
    for (int idx = tid; idx < 78*16; idx += NT) {
        int trow = idx >> 4, icq = idx & 15;
        int t = t0 - 7 + trow;
        float4 v = make_float4(0.f, 0.f, 0.f, 0.f);
        if (t >= 0 && t < 320)
            v = *reinterpret_cast<const float4*>(xb + t*64 + icq*4);
        *reinterpret_cast<float4*>(&x_lds[trow*64 + icq*4]) = v;
    }
    __syncthreads();
    // ---- depthwise conv + BN + ReLU -> y_lds[c][tt] ----
    {
        float xr[46];
        #pragma unroll
        for (int r = 0; r < 46; ++r)
            xr[r] = x_lds[(half*32 + r)*64 + (cc >> 1)];
        #pragma unroll
        for (int i = 0; i < 32; ++i) {
            float acc = 0.f;
            #pragma unroll
            for (int k = 0; k < 15; ++k)
                acc = fmaf(xr[i + k], cwr[k], acc);
            y_lds[cc*65 + half*32 + i] = fmaxf(fmaf(acc, sc1, sh1), 0.f);
        }
    }
    __syncthreads();
    // ---- projection: cur[tt=lane][h0..h0+15] ----
    {
        float acc[16];
        #pragma unroll
        for (int j = 0; j < 16; ++j) acc[j] = 0.f;
        #pragma unroll 4
        for (int c = 0; c < 128; ++c) {
            float yv = y_lds[c*65 + lane];
            const float4* wp = reinterpret_cast<const float4*>(spwT + c*64 + h0);
            float4 w0 = wp[0], w1 = wp[1], w2 = wp[2], w3 = wp[3];
            acc[0]  = fmaf(yv, w0.x, acc[0]);
            acc[1]  = fmaf(yv, w0.y, acc[1]);
            acc[2]  = fmaf(yv, w0.z, acc[2]);
            acc[3]  = fmaf(yv, w0.w, acc[3]);
            acc[4]  = fmaf(yv, w1.x, acc[4]);
            acc[5]  = fmaf(yv, w1.y, acc[5]);
            acc[6]  = fmaf(yv, w1.z, acc[6]);
            acc[7]  = fmaf(yv, w1.w, acc[7]);
            acc[8]  = fmaf(yv, w2.x, acc[8]);
            acc[9]  = fmaf(yv, w2.y, acc[9]);
            acc[10] = fmaf(yv, w2.z, acc[10]);
            acc[11] = fmaf(yv, w2.w, acc[11]);
            acc[12] = fmaf(yv, w3.x, acc[12]);
            acc[13] = fmaf(yv, w3.y, acc[13]);
            acc[14] = fmaf(yv, w3.z, acc[14]);
            acc[15] = fmaf(yv, w3.w, acc[15]);
        }
        // coalesced stores: cur[bi][h0+j][t0+lane]
        float* cb = cur + (size_t)bi * CUR_STRIDE + (size_t)h0 * 320 + t0 + lane;
        #pragma unroll
        for (int j = 0; j < 16; ++j)
            cb[j*320] = acc[j];
    }
}

// ---------------- kernel B: LIF scan, one wave per batch element ----------------
__global__ void scan_kernel(const float* __restrict__ cur,
                            const float* __restrict__ sp_b,
                            float* __restrict__ W, int b0, int nb)
{
    const int wv = (int)((blockIdx.x * (unsigned)blockDim.x + threadIdx.x) >> 6);
    if (wv >= nb) return;
    const int lane = threadIdx.x & 63;
    const float* cb = cur + (size_t)wv * CUR_STRIDE + (size_t)lane * 320;
    const float spb = sp_b[lane];
    float* Wb = W + (size_t)(b0 + wv) * 1280;

    float mf = 0.f, ms = 0.f, rlo = 0.f, rhi = 0.f;
    float4 n0 = *reinterpret_cast<const float4*>(cb);
    float4 n1 = *reinterpret_cast<const float4*>(cb + 4);
    float4 n2 = *reinterpret_cast<const float4*>(cb + 8);
    float4 n3 = *reinterpret_cast<const float4*>(cb + 12);
    float sE_lo = 0.f, sE_hi = 0.f;

    #pragma unroll 1
    for (int tb = 0; tb < 20; ++tb) {
        float v[16];
        v[0]=n0.x; v[1]=n0.y; v[2]=n0.z; v[3]=n0.w;
        v[4]=n1.x; v[5]=n1.y; v[6]=n1.z; v[7]=n1.w;
        v[8]=n2.x; v[9]=n2.y; v[10]=n2.z; v[11]=n2.w;
        v[12]=n3.x; v[13]=n3.y; v[14]=n3.z; v[15]=n3.w;
        if (tb < 19) {   // prefetch next 16 steps (one 64B line per lane)
            const float* p = cb + (tb + 1) * 16;
            n0 = *reinterpret_cast<const float4*>(p);
            n1 = *reinterpret_cast<const float4*>(p + 4);
            n2 = *reinterpret_cast<const float4*>(p + 8);
            n3 = *reinterpret_cast<const float4*>(p + 12);
        }
        float slo = 0.f, shi = 0.f;
        #pragma unroll
        for (int q = 0; q < 16; ++q) {
            float c = v[q] + spb;
            mf = fmaf(0.5f, mf, c);
            bool sf = (mf - 0.5f) >= 0.f;
            ms = fmaf(0.9f, ms, c);
            bool ss = (ms - 1.0f) >= 0.f;
            mf = sf ? 0.f : mf;
            ms = ss ? 0.f : ms;
            rlo = fmaf(0.9f, rlo, sf ? 1.f : 0.f);
            rhi = fmaf(0.9f, rhi, ss ? 1.f : 0.f);
            slo += rlo; shi += rhi;
        }
        if ((tb & 1) == 0) {
            sE_lo = slo; sE_hi = shi;
        } else {
            int w = tb >> 1;
            Wb[w*128 + lane]      = slo - sE_lo;
            Wb[w*128 + 64 + lane] = shi - sE_hi;
        }
    }
}

// ---------------- kernel C: classifier epilogue, one block per b ----------------
__global__ void epilogue_kernel(
    const float* __restrict__ tda,    const float* __restrict__ li_b,
    const float* __restrict__ tda_b1, const float* __restrict__ tda_b2,
    const float* __restrict__ cls_b1, const float* __restrict__ cls_w2,
    const float* __restrict__ cls_b2, const float* __restrict__ ws,
    const float* __restrict__ W,      float* __restrict__ out)
{
    __shared__ float Wl[1280];
    __shared__ float t1[64], tf[32], dp[640], h1[128];
    const int b = blockIdx.x, tid = threadIdx.x;

    for (int i = tid; i < 1280; i += NT)
        Wl[i] = W[(size_t)b*1280 + i];
    __syncthreads();

    const float* __restrict__ liwT = ws + WS_LIWT;
    const float* __restrict__ tw1T = ws + WS_TW1T;
    const float* __restrict__ tw2T = ws + WS_TW2T;
    const float* __restrict__ cw1T = ws + WS_CW1T;
    const float* tdab = tda + b*150;

    if (tid < 64) {                     // tda layer 1
        float acc = tda_b1[tid];
        for (int i2 = 0; i2 < 150; ++i2)
            acc = fmaf(tdab[i2], tw1T[i2*64 + tid], acc);
        t1[tid] = fmaxf(acc, 0.f);
    }
    __syncthreads();
    if (tid < 32) {                     // tda layer 2
        float acc = tda_b2[tid];
        #pragma unroll 8
        for (int j = 0; j < 64; ++j)
            acc = fmaf(t1[j], tw2T[j*32 + tid], acc);
        tf[tid] = fmaxf(acc, 0.f);
    }
    // dp_feat = (1/16) * (li_w @ W + li_b * Wg)
    {
        int o = tid & 63;
        for (int w = tid >> 6; w < 10; w += 4) {
            float acc = li_b[o] * ws[WS_WG + w];
            #pragma unroll 4
            for (int j = 0; j < 128; ++j)
                acc = fmaf(Wl[w*128 + j], liwT[j*64 + o], acc);
            dp[w*64 + o] = 0.0625f * acc;
        }
    }
    __syncthreads();
    if (tid < 128) {                    // classifier layer 1 + BN2 + ReLU
        float acc = cls_b1[tid];
        for (int j = 0; j < 640; ++j)
            acc = fmaf(dp[j], cw1T[j*128 + tid], acc);
        #pragma unroll 4
        for (int j = 0; j < 32; ++j)
            acc = fmaf(tf[j], cw1T[(640 + j)*128 + tid], acc);
        float s2 = ws[WS_SC2 + tid], sh2 = ws[WS_SH2 + tid];
        h1[tid] = fmaxf(fmaf(acc, s2, sh2), 0.f);
    }
    __syncthreads();
    if (tid < 4) {                      // classifier layer 2
        float acc = cls_b2[tid];
        for (int c = 0; c < 128; ++c)
            acc = fmaf(h1[c], cls_w2[tid*128 + c], acc);
        out[b*4 + tid] = acc;
    }
}

extern "C" void kernel_launch(void* const* d_in, const int* in_sizes, int n_in,
                              void* d_out, int out_size, void* d_ws, size_t ws_size,
                              hipStream_t stream) {
    const float* x      = (const float*)d_in[0];
    const float* tda    = (const float*)d_in[1];
    const float* conv_w = (const float*)d_in[2];
    const float* conv_b = (const float*)d_in[3];
    const float* bn1_g  = (const float*)d_in[4];
    const float* bn1_b  = (const float*)d_in[5];
    const float* bn1_m  = (const float*)d_in[6];
    const float* bn1_v  = (const float*)d_in[7];
    const float* sp_w   = (const float*)d_in[8];
    const float* sp_b   = (const float*)d_in[9];
    const float* li_w   = (const float*)d_in[10];
    const float* li_b   = (const float*)d_in[11];
    const float* tda_w1 = (const float*)d_in[12];
    const float* tda_b1 = (const float*)d_in[13];
    const float* tda_w2 = (const float*)d_in[14];
    const float* tda_b2 = (const float*)d_in[15];
    const float* cls_w1 = (const float*)d_in[16];
    const float* cls_b1 = (const float*)d_in[17];
    const float* bn2_g  = (const float*)d_in[18];
    const float* bn2_b  = (const float*)d_in[19];
    const float* bn2_m  = (const float*)d_in[20];
    const float* bn2_v  = (const float*)d_in[21];
    const float* cls_w2 = (const float*)d_in[22];
    const float* cls_b2 = (const float*)d_in[23];
    float* ws  = (float*)d_ws;
    float* out = (float*)d_out;

    const int B = in_sizes[0] / (320 * 64);   // 2048

    prep_kernel<<<(WS_TOTAL + 1 + NT - 1)/NT, NT, 0, stream>>>(
        conv_b, bn1_g, bn1_b, bn1_m, bn1_v, sp_w,
        li_w, tda_w1, tda_w2, cls_w1,
        bn2_g, bn2_b, bn2_m, bn2_v, ws);

    // batch grouping to fit cur region into ws
    long cap = (long)(ws_size / 4) - (long)WS_CURBASE;
    int nbg = (int)(cap / CUR_STRIDE);
    if (nbg < 1) nbg = 1;
    if (nbg > B) nbg = B;

    for (int g0 = 0; g0 < B; g0 += nbg) {
        int nb = (B - g0 < nbg) ? (B - g0) : nbg;
        convproj_kernel<<<nb*5, NT, 0, stream>>>(
            x, conv_w, ws, ws + WS_CURBASE, g0);
        scan_kernel<<<(nb + 3)/4, NT, 0, stream>>>(
            ws + WS_CURBASE, sp_b, ws + WS_WBASE, g0, nb);
    }

    epilogue_kernel<<<B, NT, 0, stream>>>(
        tda, li_b, tda_b1, tda_b2, cls_b1, cls_w2, cls_b2,
        ws, ws + WS_WBASE, out);
}